// Round 11
// baseline (1338.629 us; speedup 1.0000x reference)
//
#include <hip/hip_runtime.h>

typedef float f32x2 __attribute__((ext_vector_type(2)));
typedef unsigned long long u64;

#define T_STEPS 512
#define BATCH   64
#define NIN     512
#define H       1024
#define BH      (BATCH * H)   // 65536

#define BM 128
#define BN 128
#define BK 16
#define LDSS 132

// ---------------------------------------------------------------------------
// Kernel 1: transpose w_rec [j][h] -> wrecT [h][j]  (4 MB, one-time per call)
// ---------------------------------------------------------------------------
__global__ void transpose1024(const float* __restrict__ in, float* __restrict__ out) {
    __shared__ float tile[32][33];
    const int tx = threadIdx.x, ty = threadIdx.y;
    const int xg = blockIdx.x * 32 + tx;
    const int ybase = blockIdx.y * 32;
#pragma unroll
    for (int r = 0; r < 32; r += 8)
        tile[ty + r][tx] = in[(size_t)(ybase + ty + r) * H + xg];
    __syncthreads();
    const int x2 = blockIdx.y * 32 + tx;
    const int y2base = blockIdx.x * 32;
#pragma unroll
    for (int r = 0; r < 32; r += 8)
        out[(size_t)(y2base + ty + r) * H + x2] = tile[tx][ty + r];
}

// ---------------------------------------------------------------------------
// Kernel 2: cur[m][n] = sum_k x[m][k] * w_in[n][k]  (round-0 R7-verbatim)
// ---------------------------------------------------------------------------
__global__ __launch_bounds__(256) void gemm_xwin(const float* __restrict__ x,
                                                 const float* __restrict__ w,
                                                 float* __restrict__ cur) {
    __shared__ __align__(16) float As[BK][LDSS];
    __shared__ __align__(16) float Bs[BK][LDSS];
    const int tid = threadIdx.x;
    const int tx = tid & 15, ty = tid >> 4;
    const int tx4 = tx * 4, ty4 = ty * 4;
    const int m0 = blockIdx.y * BM;
    const int n0 = blockIdx.x * BN;

    float acc[8][8];
#pragma unroll
    for (int i = 0; i < 8; ++i)
#pragma unroll
        for (int j = 0; j < 8; ++j) acc[i][j] = 0.0f;

    const int ar = tid >> 2;
    const int akc = (tid & 3) * 4;

    for (int k0 = 0; k0 < NIN; k0 += BK) {
        const float4 a0 = *reinterpret_cast<const float4*>(&x[(size_t)(m0 + ar) * NIN + k0 + akc]);
        const float4 a1 = *reinterpret_cast<const float4*>(&x[(size_t)(m0 + ar + 64) * NIN + k0 + akc]);
        const float4 b0 = *reinterpret_cast<const float4*>(&w[(size_t)(n0 + ar) * NIN + k0 + akc]);
        const float4 b1 = *reinterpret_cast<const float4*>(&w[(size_t)(n0 + ar + 64) * NIN + k0 + akc]);
        __syncthreads();
        As[akc + 0][ar] = a0.x; As[akc + 1][ar] = a0.y; As[akc + 2][ar] = a0.z; As[akc + 3][ar] = a0.w;
        As[akc + 0][ar + 64] = a1.x; As[akc + 1][ar + 64] = a1.y; As[akc + 2][ar + 64] = a1.z; As[akc + 3][ar + 64] = a1.w;
        Bs[akc + 0][ar] = b0.x; Bs[akc + 1][ar] = b0.y; Bs[akc + 2][ar] = b0.z; Bs[akc + 3][ar] = b0.w;
        Bs[akc + 0][ar + 64] = b1.x; Bs[akc + 1][ar + 64] = b1.y; Bs[akc + 2][ar + 64] = b1.z; Bs[akc + 3][ar + 64] = b1.w;
        __syncthreads();

#pragma unroll
        for (int kk = 0; kk < BK; ++kk) {
            const float4 av0 = *reinterpret_cast<const float4*>(&As[kk][ty4]);
            const float4 av1 = *reinterpret_cast<const float4*>(&As[kk][ty4 + 64]);
            const float4 bv0 = *reinterpret_cast<const float4*>(&Bs[kk][tx4]);
            const float4 bv1 = *reinterpret_cast<const float4*>(&Bs[kk][tx4 + 64]);
            const float ar_[8] = {av0.x, av0.y, av0.z, av0.w, av1.x, av1.y, av1.z, av1.w};
            const float br_[8] = {bv0.x, bv0.y, bv0.z, bv0.w, bv1.x, bv1.y, bv1.z, bv1.w};
#pragma unroll
            for (int i = 0; i < 8; ++i)
#pragma unroll
                for (int j = 0; j < 8; ++j)
                    acc[i][j] = fmaf(ar_[i], br_[j], acc[i][j]);
        }
    }

#pragma unroll
    for (int gi = 0; gi < 2; ++gi)
#pragma unroll
        for (int ii = 0; ii < 4; ++ii) {
            const int i = gi * 4 + ii;
            const int row = m0 + ty4 + ii + gi * 64;
            float* dst = &cur[(size_t)row * H + n0 + tx4];
            *reinterpret_cast<float4*>(dst)      = make_float4(acc[i][0], acc[i][1], acc[i][2], acc[i][3]);
            *reinterpret_cast<float4*>(dst + 64) = make_float4(acc[i][4], acc[i][5], acc[i][6], acc[i][7]);
        }
}

// ---------------------------------------------------------------------------
// Kernel 3 (R20): COLUMN-SPLIT LSNN scan.
//   4 blocks per batch (grid 256 x 128 threads), block sub=bid&3 owns cols
//   [256*sub, 256*sub+256), 2 cols/thread (float2). Per-CU gather traffic
//   drops 4x vs R8 (the measured per-CU BW floor). Per step each block
//   publishes its 256-bit spike mask as 8 stamped u64 words (agent-scope
//   atomics, stamp = t+1, 4-slot ring) and polls the other blocks' words
//   (speculative early load; one-step slack hides most latency). All blocks
//   rebuild the SAME global ascending spike list -> accumulation order and
//   all dynamics FP ops are bit-identical to R8 (absmax 0.0).
//   Safety: all 256 blocks co-resident (<< device capacity) -> spin cannot
//   deadlock; 4-deep ring proven safe (writer at t+4 implies readers past t).
// ---------------------------------------------------------------------------
__global__ __launch_bounds__(128, 1) void lsnn_scan_kernel(float* __restrict__ io,
                                                           const float* __restrict__ wrecT,
                                                           u64* __restrict__ flags) {
    const int bid = blockIdx.x;
    const int sub = bid & 3;          // col quarter; fixed per XCD (1MB wrecT slice)
    const int batch = bid >> 2;       // 0..63
    const int tid = threadIdx.x;      // 0..127
    const int wave = tid >> 6, lane = tid & 63;
    const int span = sub * 2 + wave;  // 0..7: ascending 128-col spans of batch
    const int c0 = sub * 256 + tid * 2;

    __shared__ __align__(16) unsigned lmask[32];
    __shared__ __align__(16) int list[1056];

    float sv0 = 0.f, sv1 = 0.f;
    float si0 = 0.f, si1 = 0.f;
    float sb0 = 1.f, sb1 = 1.f;
    float sz0 = 0.f, sz1 = 0.f;

    const float C_MEM = (float)(1e-3 * 100.0);
    const float C_SYN = (float)(1e-3 * 200.0);
    const float C_AD  = (float)(1e-3 * (1.0 / 800.0));
    const float BETA  = 1.8f;

    float* base = io + (size_t)batch * H + c0;
    u64* flagsB = flags + (size_t)batch * 128;   // 4 slots x 32 words

    // chunk prefetch: 8 steps of cur (plain loads; GEMM finished before launch)
    f32x2 P0 = *(const f32x2*)(base + (size_t)0 * BH);
    f32x2 P1 = *(const f32x2*)(base + (size_t)1 * BH);
    f32x2 P2 = *(const f32x2*)(base + (size_t)2 * BH);
    f32x2 P3 = *(const f32x2*)(base + (size_t)3 * BH);
    f32x2 P4 = *(const f32x2*)(base + (size_t)4 * BH);
    f32x2 P5 = *(const f32x2*)(base + (size_t)5 * BH);
    f32x2 P6 = *(const f32x2*)(base + (size_t)6 * BH);
    f32x2 P7 = *(const f32x2*)(base + (size_t)7 * BH);

// clamped row load: positions >= n read row 0 (safe, L2-hot, masked later)
#define ROWLD(DST, POS, HV)                                                   \
    { const int hc_ = ((POS) < n) ? (HV) : 0;                                 \
      DST = *(const f32x2*)(wrecT +                                           \
            (size_t)(unsigned)__builtin_amdgcn_readfirstlane(hc_) * H + c0); }

#define LOAD16C(BUF, KT)                                                      \
  { const int A0_ = (KT) << 4;                                                \
    const int4 q0_ = *reinterpret_cast<const int4*>(list + A0_);              \
    const int4 q1_ = *reinterpret_cast<const int4*>(list + A0_ + 4);          \
    const int4 q2_ = *reinterpret_cast<const int4*>(list + A0_ + 8);          \
    const int4 q3_ = *reinterpret_cast<const int4*>(list + A0_ + 12);         \
    ROWLD(BUF[0],  A0_ + 0,  q0_.x) ROWLD(BUF[1],  A0_ + 1,  q0_.y)           \
    ROWLD(BUF[2],  A0_ + 2,  q0_.z) ROWLD(BUF[3],  A0_ + 3,  q0_.w)           \
    ROWLD(BUF[4],  A0_ + 4,  q1_.x) ROWLD(BUF[5],  A0_ + 5,  q1_.y)           \
    ROWLD(BUF[6],  A0_ + 6,  q1_.z) ROWLD(BUF[7],  A0_ + 7,  q1_.w)           \
    ROWLD(BUF[8],  A0_ + 8,  q2_.x) ROWLD(BUF[9],  A0_ + 9,  q2_.y)           \
    ROWLD(BUF[10], A0_ + 10, q2_.z) ROWLD(BUF[11], A0_ + 11, q2_.w)           \
    ROWLD(BUF[12], A0_ + 12, q3_.x) ROWLD(BUF[13], A0_ + 13, q3_.y)           \
    ROWLD(BUF[14], A0_ + 14, q3_.z) ROWLD(BUF[15], A0_ + 15, q3_.w)           \
  }

#define ACC16(BUF)                                                            \
  { _Pragma("unroll")                                                         \
    for (int k_ = 0; k_ < 16; ++k_) { r0 += BUF[k_].x; r1 += BUF[k_].y; } }

#define ACC16M(BUF, KT)                                                       \
  { const int A0m_ = (KT) << 4;                                               \
    _Pragma("unroll")                                                         \
    for (int k_ = 0; k_ < 16; ++k_) {                                         \
      const float m_ = (A0m_ + k_ < n) ? 1.0f : 0.0f;                         \
      r0 = fmaf(m_, BUF[k_].x, r0); r1 = fmaf(m_, BUF[k_].y, r1);             \
    } }

#define ACCTILE(BUF, KT)                                                      \
  { if (((((KT) << 4)) + 16) <= n) { ACC16(BUF) } else { ACC16M(BUF, KT) } }

#define SCAN_STEP(T, CREG, PF)                                                \
  {                                                                           \
    const float cc0 = CREG.x, cc1 = CREG.y;                                   \
    /* 0. speculative early poll-load for z_{T-1} masks (slot (T+3)&3) */     \
    const u64* wp_ = flagsB + ((size_t)(((T) + 3) & 3)) * 32 + tid;           \
    u64 w0_ = 0;                                                              \
    if (tid < 32)                                                             \
      w0_ = __hip_atomic_load(wp_, __ATOMIC_RELAXED, __HIP_MEMORY_SCOPE_AGENT); \
    /* 1. dynamics (bit-identical ops) */                                     \
    const float vd0 = sv0 + C_MEM * (0.0f - sv0 + si0);                       \
    const float vd1 = sv1 + C_MEM * (0.0f - sv1 + si1);                       \
    const float id0 = si0 - C_SYN * si0;                                      \
    const float id1 = si1 - C_SYN * si1;                                      \
    const float bd0 = sb0 + C_AD * (1.0f - sb0);                              \
    const float bd1 = sb1 + C_AD * (1.0f - sb1);                              \
    sz0 = ((vd0 - bd0) > 0.0f) ? 1.0f : 0.0f;                                 \
    sz1 = ((vd1 - bd1) > 0.0f) ? 1.0f : 0.0f;                                 \
    sv0 = (sz0 > 0.0f) ? 0.0f : vd0;                                          \
    sv1 = (sz1 > 0.0f) ? 0.0f : vd1;                                          \
    sb0 = (sz0 > 0.0f) ? (bd0 + BETA) : bd0;                                  \
    sb1 = (sz1 > 0.0f) ? (bd1 + BETA) : bd1;                                  \
    /* 2. publish this block's masks (stamp T+1, slot T&3) */                 \
    const u64 m0_ = __ballot(sz0 > 0.0f);                                     \
    const u64 m1_ = __ballot(sz1 > 0.0f);                                     \
    if (lane < 4) {                                                           \
      const u64 mm_ = (lane < 2) ? m0_ : m1_;                                 \
      const unsigned pay_ = (lane & 1) ? (unsigned)(mm_ >> 32) : (unsigned)mm_; \
      const u64 word_ = ((u64)(unsigned)((T) + 1) << 32) | (u64)pay_;         \
      __hip_atomic_store(flagsB + ((size_t)((T) & 3)) * 32 + span * 4 + lane, \
                         word_, __ATOMIC_RELAXED, __HIP_MEMORY_SCOPE_AGENT);  \
    }                                                                         \
    /* 3. z store + chunk prefetch issue */                                   \
    *reinterpret_cast<f32x2*>(base + (size_t)(T) * BH) = (f32x2){sz0, sz1};   \
    if (PF) {                                                                 \
      if ((T) + 1 < T_STEPS) {                                                \
        const float* pb = base + (size_t)((T) + 1) * BH;                      \
        P0 = *(const f32x2*)(pb + (size_t)0 * BH);                            \
        P1 = *(const f32x2*)(pb + (size_t)1 * BH);                            \
        P2 = *(const f32x2*)(pb + (size_t)2 * BH);                            \
        P3 = *(const f32x2*)(pb + (size_t)3 * BH);                            \
        P4 = *(const f32x2*)(pb + (size_t)4 * BH);                            \
        P5 = *(const f32x2*)(pb + (size_t)5 * BH);                            \
        P6 = *(const f32x2*)(pb + (size_t)6 * BH);                            \
        P7 = *(const f32x2*)(pb + (size_t)7 * BH);                            \
      }                                                                       \
    }                                                                         \
    /* 4. complete poll (expect stamp T = z_{T-1}) */                         \
    if (tid < 32) {                                                           \
      u64 wv_ = w0_;                                                          \
      if ((unsigned)(wv_ >> 32) != (unsigned)(T)) {                           \
        for (int tr_ = 0; tr_ < (1 << 20); ++tr_) {                           \
          wv_ = __hip_atomic_load(wp_, __ATOMIC_RELAXED,                      \
                                  __HIP_MEMORY_SCOPE_AGENT);                  \
          if ((unsigned)(wv_ >> 32) == (unsigned)(T)) break;                  \
          __builtin_amdgcn_s_sleep(2);                                        \
        }                                                                     \
      }                                                                       \
      lmask[tid] = (unsigned)wv_;                                             \
    }                                                                         \
    __syncthreads();                                                          \
    /* 5. rebuild global ascending spike list (same order as R8) */           \
    int n;                                                                    \
    {                                                                         \
      const int s_ = tid >> 4;                                                \
      const int l0_ = (tid & 15) * 4;                                         \
      int basep_ = 0, nn_ = 0;                                                \
      u64 a_own_ = 0, b_own_ = 0;                                             \
      _Pragma("unroll")                                                       \
      for (int ss_ = 0; ss_ < 8; ++ss_) {                                     \
        const u64 a_ = (u64)lmask[ss_ * 4] | ((u64)lmask[ss_ * 4 + 1] << 32); \
        const u64 b_ = (u64)lmask[ss_ * 4 + 2] | ((u64)lmask[ss_ * 4 + 3] << 32); \
        const int c_ = __popcll(a_) + __popcll(b_);                           \
        nn_ += c_;                                                            \
        if (ss_ < s_) basep_ += c_;                                           \
        if (ss_ == s_) { a_own_ = a_; b_own_ = b_; }                          \
      }                                                                       \
      n = nn_;                                                                \
      const u64 pm_ = (l0_ == 0) ? 0ull : ((1ull << l0_) - 1ull);             \
      int pos_ = basep_ + __popcll(a_own_ & pm_) + __popcll(b_own_ & pm_);    \
      _Pragma("unroll")                                                       \
      for (int dl_ = 0; dl_ < 4; ++dl_) {                                     \
        const int l_ = l0_ + dl_;                                             \
        if ((a_own_ >> l_) & 1) list[pos_++] = s_ * 128 + 2 * l_;             \
        if ((b_own_ >> l_) & 1) list[pos_++] = s_ * 128 + 2 * l_ + 1;         \
      }                                                                       \
    }                                                                         \
    __syncthreads();                                                          \
    /* 6. gather over this block's 256-col slice (2-deep x 16 pipeline) */    \
    float r0 = 0.f, r1 = 0.f;                                                 \
    {                                                                         \
      const int NT = (n + 15) >> 4;                                           \
      f32x2 wA[16], wB[16];                                                   \
      if (n > 0) {                                                            \
        LOAD16C(wA, 0);                                                       \
        LOAD16C(wB, 1);                                                       \
        int kt = 0;                                                           \
        for (; kt + 2 < NT; kt += 2) {                                        \
          ACCTILE(wA, kt);     LOAD16C(wA, kt + 2);                           \
          ACCTILE(wB, kt + 1); LOAD16C(wB, kt + 3);                           \
        }                                                                     \
        ACCTILE(wA, kt);                                                      \
        if (kt + 1 < NT) ACCTILE(wB, kt + 1);                                 \
      }                                                                       \
    }                                                                         \
    /* 7. si update (same op order as R8) */                                  \
    si0 = (id0 + cc0) + r0;                                                   \
    si1 = (id1 + cc1) + r1;                                                   \
  }

    for (int t = 0; t < T_STEPS; t += 8) {
        SCAN_STEP(t,     P0, 0);
        SCAN_STEP(t + 1, P1, 0);
        SCAN_STEP(t + 2, P2, 0);
        SCAN_STEP(t + 3, P3, 0);
        SCAN_STEP(t + 4, P4, 0);
        SCAN_STEP(t + 5, P5, 0);
        SCAN_STEP(t + 6, P6, 0);
        SCAN_STEP(t + 7, P7, 1);
    }
#undef SCAN_STEP
#undef ACCTILE
#undef ACC16M
#undef ACC16
#undef LOAD16C
#undef ROWLD

    float* fo = io + (size_t)T_STEPS * BH + (size_t)batch * H + c0;
    *reinterpret_cast<f32x2*>(fo)          = (f32x2){sz0, sz1};
    *reinterpret_cast<f32x2*>(fo + BH)     = (f32x2){sv0, sv1};
    *reinterpret_cast<f32x2*>(fo + 2 * BH) = (f32x2){si0, si1};
    *reinterpret_cast<f32x2*>(fo + 3 * BH) = (f32x2){sb0, sb1};
}

// ---------------------------------------------------------------------------
extern "C" void kernel_launch(void* const* d_in, const int* in_sizes, int n_in,
                              void* d_out, int out_size, void* d_ws, size_t ws_size,
                              hipStream_t stream) {
    const float* x     = (const float*)d_in[0];
    const float* w_in  = (const float*)d_in[1];
    const float* w_rec = (const float*)d_in[2];
    float* out   = (float*)d_out;
    float* wrecT = (float*)d_ws;
    u64*   flags = (u64*)((char*)d_ws + (size_t)H * H * sizeof(float));  // ws+4MB

    // zero the mask-exchange flags (64 batches x 4 slots x 32 words x 8 B = 64 KiB)
    hipMemsetAsync(flags, 0, (size_t)BATCH * 4 * 32 * sizeof(u64), stream);
    transpose1024<<<dim3(H / 32, H / 32), dim3(32, 8), 0, stream>>>(w_rec, wrecT);
    gemm_xwin<<<dim3(H / BN, (T_STEPS * BATCH) / BM), 256, 0, stream>>>(x, w_in, out);
    lsnn_scan_kernel<<<dim3(BATCH * 4), 128, 0, stream>>>(out, wrecT, flags);
}

// Round 12
// 755.400 us; speedup vs baseline: 1.7721x; 1.7721x over previous
//
#include <hip/hip_runtime.h>

typedef float f32x4 __attribute__((ext_vector_type(4)));

#define T_STEPS 512
#define BATCH   64
#define NIN     512
#define H       1024
#define BH      (BATCH * H)   // 65536

#define BM 128
#define BN 128
#define BK 16
#define LDSS 132

// ---------------------------------------------------------------------------
// Kernel 1: transpose w_rec [j][h] -> wrecT [h][j]  (4 MB, one-time per call)
// ---------------------------------------------------------------------------
__global__ void transpose1024(const float* __restrict__ in, float* __restrict__ out) {
    __shared__ float tile[32][33];
    const int tx = threadIdx.x, ty = threadIdx.y;
    const int xg = blockIdx.x * 32 + tx;
    const int ybase = blockIdx.y * 32;
#pragma unroll
    for (int r = 0; r < 32; r += 8)
        tile[ty + r][tx] = in[(size_t)(ybase + ty + r) * H + xg];
    __syncthreads();
    const int x2 = blockIdx.y * 32 + tx;
    const int y2base = blockIdx.x * 32;
#pragma unroll
    for (int r = 0; r < 32; r += 8)
        out[(size_t)(y2base + ty + r) * H + x2] = tile[tx][ty + r];
}

// ---------------------------------------------------------------------------
// Kernel 2: cur[m][n] = sum_k x[m][k] * w_in[n][k]  (round-0 R7-verbatim)
// ---------------------------------------------------------------------------
__global__ __launch_bounds__(256) void gemm_xwin(const float* __restrict__ x,
                                                 const float* __restrict__ w,
                                                 float* __restrict__ cur) {
    __shared__ __align__(16) float As[BK][LDSS];
    __shared__ __align__(16) float Bs[BK][LDSS];
    const int tid = threadIdx.x;
    const int tx = tid & 15, ty = tid >> 4;
    const int tx4 = tx * 4, ty4 = ty * 4;
    const int m0 = blockIdx.y * BM;
    const int n0 = blockIdx.x * BN;

    float acc[8][8];
#pragma unroll
    for (int i = 0; i < 8; ++i)
#pragma unroll
        for (int j = 0; j < 8; ++j) acc[i][j] = 0.0f;

    const int ar = tid >> 2;
    const int akc = (tid & 3) * 4;

    for (int k0 = 0; k0 < NIN; k0 += BK) {
        const float4 a0 = *reinterpret_cast<const float4*>(&x[(size_t)(m0 + ar) * NIN + k0 + akc]);
        const float4 a1 = *reinterpret_cast<const float4*>(&x[(size_t)(m0 + ar + 64) * NIN + k0 + akc]);
        const float4 b0 = *reinterpret_cast<const float4*>(&w[(size_t)(n0 + ar) * NIN + k0 + akc]);
        const float4 b1 = *reinterpret_cast<const float4*>(&w[(size_t)(n0 + ar + 64) * NIN + k0 + akc]);
        __syncthreads();
        As[akc + 0][ar] = a0.x; As[akc + 1][ar] = a0.y; As[akc + 2][ar] = a0.z; As[akc + 3][ar] = a0.w;
        As[akc + 0][ar + 64] = a1.x; As[akc + 1][ar + 64] = a1.y; As[akc + 2][ar + 64] = a1.z; As[akc + 3][ar + 64] = a1.w;
        Bs[akc + 0][ar] = b0.x; Bs[akc + 1][ar] = b0.y; Bs[akc + 2][ar] = b0.z; Bs[akc + 3][ar] = b0.w;
        Bs[akc + 0][ar + 64] = b1.x; Bs[akc + 1][ar + 64] = b1.y; Bs[akc + 2][ar + 64] = b1.z; Bs[akc + 3][ar + 64] = b1.w;
        __syncthreads();

#pragma unroll
        for (int kk = 0; kk < BK; ++kk) {
            const float4 av0 = *reinterpret_cast<const float4*>(&As[kk][ty4]);
            const float4 av1 = *reinterpret_cast<const float4*>(&As[kk][ty4 + 64]);
            const float4 bv0 = *reinterpret_cast<const float4*>(&Bs[kk][tx4]);
            const float4 bv1 = *reinterpret_cast<const float4*>(&Bs[kk][tx4 + 64]);
            const float ar_[8] = {av0.x, av0.y, av0.z, av0.w, av1.x, av1.y, av1.z, av1.w};
            const float br_[8] = {bv0.x, bv0.y, bv0.z, bv0.w, bv1.x, bv1.y, bv1.z, bv1.w};
#pragma unroll
            for (int i = 0; i < 8; ++i)
#pragma unroll
                for (int j = 0; j < 8; ++j)
                    acc[i][j] = fmaf(ar_[i], br_[j], acc[i][j]);
        }
    }

#pragma unroll
    for (int gi = 0; gi < 2; ++gi)
#pragma unroll
        for (int ii = 0; ii < 4; ++ii) {
            const int i = gi * 4 + ii;
            const int row = m0 + ty4 + ii + gi * 64;
            float* dst = &cur[(size_t)row * H + n0 + tx4];
            *reinterpret_cast<float4*>(dst)      = make_float4(acc[i][0], acc[i][1], acc[i][2], acc[i][3]);
            *reinterpret_cast<float4*>(dst + 64) = make_float4(acc[i][4], acc[i][5], acc[i][6], acc[i][7]);
        }
}

// ---------------------------------------------------------------------------
// Kernel 3 (R21): scan with ASYNC-LDS ring-pipelined gather.
//   One block per batch (R8 structure — R20 proved cross-CU sync per step is
//   unaffordable). The gather uses __builtin_amdgcn_global_load_lds (width
//   16): rows land directly in a 3-slot x 4-row x 4KB LDS ring, ZERO gather
//   VGPRs -> the register-pressure failure of R9/R10/R12 cannot recur, and
//   the pipeline is enforced by counted `s_waitcnt vmcnt(8/4/0)` the
//   compiler cannot re-serialize. Each wave stages & reads only its own 1KB
//   row-quarter (lds dest = uniform base + lane*16 == read layout) -> no
//   barriers inside the gather. Groups 0..2 issue at the step top so the
//   dynamics + ballot + 2 raw-barrier compaction (no vmcnt drain) hide the
//   first load latency. Merged-list compaction + clamped rows + fmaf-masked
//   tail are R12-verbatim (bit-exact verified); accumulation order = flat
//   ascending list = R8 order (absmax 0.0).
// ---------------------------------------------------------------------------
__global__ __launch_bounds__(256, 1) void lsnn_scan_kernel(float* __restrict__ io,
                                                           const float* __restrict__ wrecT) {
    const int tid = threadIdx.x;
    const int wave = tid >> 6, lane = tid & 63;
    const int j0 = tid * 4;
    const int wq = wave * 256;          // this wave's column quarter (floats)
    const int b = blockIdx.x;

    __shared__ __align__(16) float ring[3][4][1024];   // 48 KB gather ring
    __shared__ __align__(16) int list[2][1088];        // merged spike list
    __shared__ __align__(16) int cnt[2][4];

    float sv0 = 0.f, sv1 = 0.f, sv2 = 0.f, sv3 = 0.f;
    float si0 = 0.f, si1 = 0.f, si2 = 0.f, si3 = 0.f;
    float sb0 = 1.f, sb1 = 1.f, sb2 = 1.f, sb3 = 1.f;
    float sz0 = 0.f, sz1 = 0.f, sz2 = 0.f, sz3 = 0.f;
    int p = 0;
    int n_carry = 0;

    const float C_MEM = (float)(1e-3 * 100.0);
    const float C_SYN = (float)(1e-3 * 200.0);
    const float C_AD  = (float)(1e-3 * (1.0 / 800.0));
    const float BETA  = 1.8f;

    float* base = io + (size_t)b * H + j0;

    // chunk prefetch buffers: 8 steps of cur (plain loads; GEMM ran before us)
    f32x4 P0 = *reinterpret_cast<const f32x4*>(base + (size_t)0 * BH);
    f32x4 P1 = *reinterpret_cast<const f32x4*>(base + (size_t)1 * BH);
    f32x4 P2 = *reinterpret_cast<const f32x4*>(base + (size_t)2 * BH);
    f32x4 P3 = *reinterpret_cast<const f32x4*>(base + (size_t)3 * BH);
    f32x4 P4 = *reinterpret_cast<const f32x4*>(base + (size_t)4 * BH);
    f32x4 P5 = *reinterpret_cast<const f32x4*>(base + (size_t)5 * BH);
    f32x4 P6 = *reinterpret_cast<const f32x4*>(base + (size_t)6 * BH);
    f32x4 P7 = *reinterpret_cast<const f32x4*>(base + (size_t)7 * BH);

// stage group G (4 rows) into ring slot SLOT: per wave, 4 global_load_lds of
// this wave's 1KB quarter. Row index clamped to 0 for positions >= n
// (always-issued, safe, L2-hot; masked at accumulate — exact).
#define STAGE(G, SLOT)                                                        \
  { const int A0s_ = (G) << 2;                                                \
    _Pragma("unroll")                                                         \
    for (int rr_ = 0; rr_ < 4; ++rr_) {                                       \
      const int ps_ = A0s_ + rr_;                                             \
      int hs_ = lst[ps_];                                                     \
      hs_ = (ps_ < n) ? hs_ : 0;                                              \
      const float* gp_ = wrecT + (size_t)(unsigned)hs_ * H + wq + lane * 4;   \
      __builtin_amdgcn_global_load_lds(                                       \
          (const __attribute__((address_space(1))) unsigned int*)gp_,         \
          (__attribute__((address_space(3))) unsigned int*)&ring[SLOT][rr_][wq], \
          16, 0, 0);                                                          \
    } }

#define SCAN_STEP(T, CREG, PF)                                                \
  {                                                                           \
    const float cc0 = CREG.x, cc1 = CREG.y, cc2 = CREG.z, cc3 = CREG.w;       \
    const int n = __builtin_amdgcn_readfirstlane(n_carry);                    \
    const int NT = (n + 3) >> 2;                                              \
    const int* lst = &list[p][0];                                             \
    /* issue first three groups NOW; latency hides under dynamics+barriers */ \
    if (NT > 0) STAGE(0, 0);                                                  \
    if (NT > 1) STAGE(1, 1);                                                  \
    if (NT > 2) STAGE(2, 2);                                                  \
    /* dynamics (bit-identical ops, R8 order) */                              \
    const float vd0 = sv0 + C_MEM * (0.0f - sv0 + si0);                       \
    const float vd1 = sv1 + C_MEM * (0.0f - sv1 + si1);                       \
    const float vd2 = sv2 + C_MEM * (0.0f - sv2 + si2);                       \
    const float vd3 = sv3 + C_MEM * (0.0f - sv3 + si3);                       \
    const float id0 = si0 - C_SYN * si0;                                      \
    const float id1 = si1 - C_SYN * si1;                                      \
    const float id2 = si2 - C_SYN * si2;                                      \
    const float id3 = si3 - C_SYN * si3;                                      \
    const float bd0 = sb0 + C_AD * (1.0f - sb0);                              \
    const float bd1 = sb1 + C_AD * (1.0f - sb1);                              \
    const float bd2 = sb2 + C_AD * (1.0f - sb2);                              \
    const float bd3 = sb3 + C_AD * (1.0f - sb3);                              \
    sz0 = ((vd0 - bd0) > 0.0f) ? 1.0f : 0.0f;                                 \
    sz1 = ((vd1 - bd1) > 0.0f) ? 1.0f : 0.0f;                                 \
    sz2 = ((vd2 - bd2) > 0.0f) ? 1.0f : 0.0f;                                 \
    sz3 = ((vd3 - bd3) > 0.0f) ? 1.0f : 0.0f;                                 \
    sv0 = (sz0 > 0.0f) ? 0.0f : vd0;                                          \
    sv1 = (sz1 > 0.0f) ? 0.0f : vd1;                                          \
    sv2 = (sz2 > 0.0f) ? 0.0f : vd2;                                          \
    sv3 = (sz3 > 0.0f) ? 0.0f : vd3;                                          \
    sb0 = (sz0 > 0.0f) ? (bd0 + BETA) : bd0;                                  \
    sb1 = (sz1 > 0.0f) ? (bd1 + BETA) : bd1;                                  \
    sb2 = (sz2 > 0.0f) ? (bd2 + BETA) : bd2;                                  \
    sb3 = (sz3 > 0.0f) ? (bd3 + BETA) : bd3;                                  \
    *reinterpret_cast<f32x4*>(base + (size_t)(T) * BH) =                      \
        (f32x4){sz0, sz1, sz2, sz3};                                          \
    const unsigned long long m0 = __ballot(sz0 > 0.0f);                       \
    const unsigned long long m1 = __ballot(sz1 > 0.0f);                       \
    const unsigned long long m2 = __ballot(sz2 > 0.0f);                       \
    const unsigned long long m3 = __ballot(sz3 > 0.0f);                       \
    unsigned pos = __builtin_amdgcn_mbcnt_hi((unsigned)(m0 >> 32),            \
                   __builtin_amdgcn_mbcnt_lo((unsigned)m0, 0u));              \
    pos = __builtin_amdgcn_mbcnt_hi((unsigned)(m1 >> 32),                     \
          __builtin_amdgcn_mbcnt_lo((unsigned)m1, pos));                      \
    pos = __builtin_amdgcn_mbcnt_hi((unsigned)(m2 >> 32),                     \
          __builtin_amdgcn_mbcnt_lo((unsigned)m2, pos));                      \
    pos = __builtin_amdgcn_mbcnt_hi((unsigned)(m3 >> 32),                     \
          __builtin_amdgcn_mbcnt_lo((unsigned)m3, pos));                      \
    if (lane == 0)                                                            \
      cnt[p ^ 1][wave] = __popcll(m0) + __popcll(m1) + __popcll(m2) + __popcll(m3); \
    asm volatile("s_waitcnt lgkmcnt(0)" ::: "memory");                        \
    __builtin_amdgcn_s_barrier();                                             \
    const int4 nc = *reinterpret_cast<const int4*>(&cnt[p ^ 1][0]);           \
    n_carry = nc.x + nc.y + nc.z + nc.w;                                      \
    const int woff = (wave > 0 ? nc.x : 0) + (wave > 1 ? nc.y : 0) +          \
                     (wave > 2 ? nc.z : 0);                                   \
    int* dst = &list[p ^ 1][woff];                                            \
    if (sz0 > 0.0f) dst[pos++] = j0 + 0;                                      \
    if (sz1 > 0.0f) dst[pos++] = j0 + 1;                                      \
    if (sz2 > 0.0f) dst[pos++] = j0 + 2;                                      \
    if (sz3 > 0.0f) dst[pos++] = j0 + 3;                                      \
    asm volatile("s_waitcnt lgkmcnt(0)" ::: "memory");                        \
    __builtin_amdgcn_s_barrier();                                             \
    /* ring-pipelined gather: read g while g+1,g+2 in flight; stage g+3 */    \
    float r0 = 0.f, r1 = 0.f, r2 = 0.f, r3 = 0.f;                             \
    {                                                                         \
      int sl = 0;                                                             \
      for (int g = 0; g < NT; ++g) {                                          \
        const int rem = NT - 1 - g;                                           \
        if (rem >= 2)      { asm volatile("s_waitcnt vmcnt(8)" ::: "memory"); } \
        else if (rem == 1) { asm volatile("s_waitcnt vmcnt(4)" ::: "memory"); } \
        else               { asm volatile("s_waitcnt vmcnt(0)" ::: "memory"); } \
        const f32x4 w0 = *reinterpret_cast<const f32x4*>(&ring[sl][0][j0]);   \
        const f32x4 w1 = *reinterpret_cast<const f32x4*>(&ring[sl][1][j0]);   \
        const f32x4 w2 = *reinterpret_cast<const f32x4*>(&ring[sl][2][j0]);   \
        const f32x4 w3 = *reinterpret_cast<const f32x4*>(&ring[sl][3][j0]);   \
        const int gb = g << 2;                                                \
        if (gb + 4 <= n) {                                                    \
          r0 += w0.x; r1 += w0.y; r2 += w0.z; r3 += w0.w;                     \
          r0 += w1.x; r1 += w1.y; r2 += w1.z; r3 += w1.w;                     \
          r0 += w2.x; r1 += w2.y; r2 += w2.z; r3 += w2.w;                     \
          r0 += w3.x; r1 += w3.y; r2 += w3.z; r3 += w3.w;                     \
        } else {                                                              \
          const float ma_ = (gb + 0 < n) ? 1.0f : 0.0f;                       \
          r0 = fmaf(ma_, w0.x, r0); r1 = fmaf(ma_, w0.y, r1);                 \
          r2 = fmaf(ma_, w0.z, r2); r3 = fmaf(ma_, w0.w, r3);                 \
          const float mb_ = (gb + 1 < n) ? 1.0f : 0.0f;                       \
          r0 = fmaf(mb_, w1.x, r0); r1 = fmaf(mb_, w1.y, r1);                 \
          r2 = fmaf(mb_, w1.z, r2); r3 = fmaf(mb_, w1.w, r3);                 \
          const float mc_ = (gb + 2 < n) ? 1.0f : 0.0f;                       \
          r0 = fmaf(mc_, w2.x, r0); r1 = fmaf(mc_, w2.y, r1);                 \
          r2 = fmaf(mc_, w2.z, r2); r3 = fmaf(mc_, w2.w, r3);                 \
          const float md_ = (gb + 3 < n) ? 1.0f : 0.0f;                       \
          r0 = fmaf(md_, w3.x, r0); r1 = fmaf(md_, w3.y, r1);                 \
          r2 = fmaf(md_, w3.z, r2); r3 = fmaf(md_, w3.w, r3);                 \
        }                                                                     \
        if (g + 3 < NT) {                                                     \
          /* slot sl is fully consumed (adds forced lgkm wait); reuse it */   \
          asm volatile("s_waitcnt lgkmcnt(0)" ::: "memory");                  \
          STAGE(g + 3, sl);                                                   \
        }                                                                     \
        sl = (sl == 2) ? 0 : sl + 1;                                          \
      }                                                                       \
    }                                                                         \
    if (PF) {                                                                 \
      if ((T) + 1 < T_STEPS) {                                                \
        const float* pb = base + (size_t)((T) + 1) * BH;                      \
        P0 = *(const f32x4*)(pb + (size_t)0 * BH);                            \
        P1 = *(const f32x4*)(pb + (size_t)1 * BH);                            \
        P2 = *(const f32x4*)(pb + (size_t)2 * BH);                            \
        P3 = *(const f32x4*)(pb + (size_t)3 * BH);                            \
        P4 = *(const f32x4*)(pb + (size_t)4 * BH);                            \
        P5 = *(const f32x4*)(pb + (size_t)5 * BH);                            \
        P6 = *(const f32x4*)(pb + (size_t)6 * BH);                            \
        P7 = *(const f32x4*)(pb + (size_t)7 * BH);                            \
      }                                                                       \
    }                                                                         \
    si0 = (id0 + cc0) + r0;                                                   \
    si1 = (id1 + cc1) + r1;                                                   \
    si2 = (id2 + cc2) + r2;                                                   \
    si3 = (id3 + cc3) + r3;                                                   \
    p ^= 1;                                                                   \
  }

    for (int t = 0; t < T_STEPS; t += 8) {
        SCAN_STEP(t,     P0, 0);
        SCAN_STEP(t + 1, P1, 0);
        SCAN_STEP(t + 2, P2, 0);
        SCAN_STEP(t + 3, P3, 0);
        SCAN_STEP(t + 4, P4, 0);
        SCAN_STEP(t + 5, P5, 0);
        SCAN_STEP(t + 6, P6, 0);
        SCAN_STEP(t + 7, P7, 1);
    }
#undef SCAN_STEP
#undef STAGE

    float* fo = io + (size_t)T_STEPS * BH + (size_t)b * H + j0;
    *reinterpret_cast<float4*>(fo)          = make_float4(sz0, sz1, sz2, sz3);
    *reinterpret_cast<float4*>(fo + BH)     = make_float4(sv0, sv1, sv2, sv3);
    *reinterpret_cast<float4*>(fo + 2 * BH) = make_float4(si0, si1, si2, si3);
    *reinterpret_cast<float4*>(fo + 3 * BH) = make_float4(sb0, sb1, sb2, sb3);
}

// ---------------------------------------------------------------------------
extern "C" void kernel_launch(void* const* d_in, const int* in_sizes, int n_in,
                              void* d_out, int out_size, void* d_ws, size_t ws_size,
                              hipStream_t stream) {
    const float* x     = (const float*)d_in[0];
    const float* w_in  = (const float*)d_in[1];
    const float* w_rec = (const float*)d_in[2];
    float* out   = (float*)d_out;
    float* wrecT = (float*)d_ws;

    transpose1024<<<dim3(H / 32, H / 32), dim3(32, 8), 0, stream>>>(w_rec, wrecT);
    gemm_xwin<<<dim3(H / BN, (T_STEPS * BATCH) / BM), 256, 0, stream>>>(x, w_in, out);
    lsnn_scan_kernel<<<BATCH, 256, 0, stream>>>(out, wrecT);
}